// Round 1
// baseline (685.479 us; speedup 1.0000x reference)
//
#include <hip/hip_runtime.h>

// Problem: B=4096, K=64, DIM=512, obj=0:
//   out = sum_{b, k != labels[b]} exp( -sum_d (inputs[b,d] - decoded[b,k,d])^2 )
// Memory-bound: decoded = 512 MiB dominates. Floor ~87 us @ 6.3 TB/s.

#define B_SZ 4096
#define K_SZ 64
#define DIM  512

__global__ __launch_bounds__(256) void score_kernel(
    const float* __restrict__ inputs,   // (B, DIM)
    const float* __restrict__ decoded,  // (B, K, DIM)
    const int*   __restrict__ labels,   // (B,)
    float* __restrict__ partials)       // (B,) in workspace
{
    const int b    = blockIdx.x;
    const int tid  = threadIdx.x;
    const int wave = tid >> 6;   // 0..3
    const int lane = tid & 63;

    // Cache this block's input row in registers: lane l holds floats
    // [4l,4l+4) and [256+4l, 256+4l+4).  Two coalesced 16B loads.
    const float4* inp = (const float4*)(inputs + (size_t)b * DIM);
    const float4 in1 = inp[lane];
    const float4 in2 = inp[64 + lane];

    const int lab = labels[b];

    const float4* dec = (const float4*)(decoded + (size_t)b * K_SZ * DIM);
    float acc = 0.0f;

    // wave w handles k = w, w+4, ... (16 iterations); the block's 4 waves
    // touch 4 consecutive 2KiB rows per round -> contiguous 8KiB chunks.
    for (int k = wave; k < K_SZ; k += 4) {
        const float4* row = dec + (size_t)k * (DIM / 4);
        const float4 d1 = row[lane];        // 64 lanes x 16B = 1KiB contiguous
        const float4 d2 = row[64 + lane];

        float dx, s;
        dx = in1.x - d1.x; s  = dx * dx;
        dx = in1.y - d1.y; s += dx * dx;
        dx = in1.z - d1.z; s += dx * dx;
        dx = in1.w - d1.w; s += dx * dx;
        dx = in2.x - d2.x; s += dx * dx;
        dx = in2.y - d2.y; s += dx * dx;
        dx = in2.z - d2.z; s += dx * dx;
        dx = in2.w - d2.w; s += dx * dx;

        // butterfly across the 64-lane wave: every lane ends with full sum
        #pragma unroll
        for (int off = 32; off; off >>= 1)
            s += __shfl_xor(s, off, 64);

        if (k != lab) acc += expf(-s);
    }

    // acc is wave-uniform; one lane per wave publishes, thread 0 combines.
    __shared__ float wacc[4];
    if (lane == 0) wacc[wave] = acc;
    __syncthreads();
    if (tid == 0) partials[b] = wacc[0] + wacc[1] + wacc[2] + wacc[3];
}

__global__ __launch_bounds__(256) void reduce_kernel(
    const float* __restrict__ partials, float* __restrict__ out)
{
    float s = 0.0f;
    for (int i = threadIdx.x; i < B_SZ; i += 256) s += partials[i];
    #pragma unroll
    for (int off = 32; off; off >>= 1)
        s += __shfl_xor(s, off, 64);
    __shared__ float wacc[4];
    const int wave = threadIdx.x >> 6, lane = threadIdx.x & 63;
    if (lane == 0) wacc[wave] = s;
    __syncthreads();
    if (threadIdx.x == 0) out[0] = wacc[0] + wacc[1] + wacc[2] + wacc[3];
}

extern "C" void kernel_launch(void* const* d_in, const int* in_sizes, int n_in,
                              void* d_out, int out_size, void* d_ws, size_t ws_size,
                              hipStream_t stream) {
    const float* inputs  = (const float*)d_in[0];
    const float* decoded = (const float*)d_in[1];
    const int*   labels  = (const int*)d_in[2];
    // d_in[3] is obj (==0 in setup) -> obj=False branch implemented.
    float* out      = (float*)d_out;
    float* partials = (float*)d_ws;   // B_SZ floats, fully overwritten each call

    score_kernel<<<B_SZ, 256, 0, stream>>>(inputs, decoded, labels, partials);
    reduce_kernel<<<1, 256, 0, stream>>>(partials, out);
}

// Round 2
// 683.178 us; speedup vs baseline: 1.0034x; 1.0034x over previous
//
#include <hip/hip_runtime.h>

// Problem: B=4096, K=64, DIM=512, obj=0:
//   out = sum_{b, k != labels[b]} exp( -sum_d (inputs[b,d] - decoded[b,k,d])^2 )
// Memory-bound: decoded = 512 MiB dominates. Kernel floor ~85 us @ 6.3 TB/s.
// R1: deferred cross-lane reduction — load loop is pure streaming FMA
// (no ds_swizzle between loads), butterflies batched at the end (16
// independent chains, fully pipelined).

#define B_SZ 4096
#define K_SZ 64
#define DIM  512

__global__ __launch_bounds__(256) void score_kernel(
    const float* __restrict__ inputs,   // (B, DIM)
    const float* __restrict__ decoded,  // (B, K, DIM)
    const int*   __restrict__ labels,   // (B,)
    float* __restrict__ partials)       // (B,) in workspace
{
    const int b    = blockIdx.x;
    const int tid  = threadIdx.x;
    const int wave = tid >> 6;   // 0..3
    const int lane = tid & 63;

    // Lane l caches inputs[b, 4l:4l+4) and inputs[b, 256+4l : 256+4l+4).
    const float4* inp = (const float4*)(inputs + (size_t)b * DIM);
    const float4 in1 = inp[lane];
    const float4 in2 = inp[64 + lane];

    const int lab = labels[b];
    const float4* dec = (const float4*)(decoded + (size_t)b * K_SZ * DIM);

    // Phase 1: pure streaming. Wave w owns k = w, w+4, ..., w+60.
    // Each lane keeps a private 8-dim partial per k — no cross-lane ops here,
    // so the 32 global_load_dwordx4 pipeline freely.
    float sk[16];
    #pragma unroll
    for (int j = 0; j < 16; ++j) {
        const int k = wave + 4 * j;
        const float4* row = dec + (size_t)k * (DIM / 4);
        const float4 d1 = row[lane];        // 64 lanes x 16B = 1KiB contiguous
        const float4 d2 = row[64 + lane];

        float dx, s;
        dx = in1.x - d1.x; s  = dx * dx;
        dx = in1.y - d1.y; s += dx * dx;
        dx = in1.z - d1.z; s += dx * dx;
        dx = in1.w - d1.w; s += dx * dx;
        dx = in2.x - d2.x; s += dx * dx;
        dx = in2.y - d2.y; s += dx * dx;
        dx = in2.z - d2.z; s += dx * dx;
        dx = in2.w - d2.w; s += dx * dx;
        sk[j] = s;
    }

    // Phase 2: 16 independent 6-stage butterflies (pipelined, ILP=16).
    float acc = 0.0f;
    #pragma unroll
    for (int j = 0; j < 16; ++j) {
        float s = sk[j];
        #pragma unroll
        for (int off = 32; off; off >>= 1)
            s += __shfl_xor(s, off, 64);
        const int k = wave + 4 * j;
        acc += (k != lab) ? expf(-s) : 0.0f;   // wave-uniform, branchless
    }

    // acc is wave-uniform; one lane per wave publishes, thread 0 combines.
    __shared__ float wacc[4];
    if (lane == 0) wacc[wave] = acc;
    __syncthreads();
    if (tid == 0) partials[b] = wacc[0] + wacc[1] + wacc[2] + wacc[3];
}

__global__ __launch_bounds__(256) void reduce_kernel(
    const float* __restrict__ partials, float* __restrict__ out)
{
    float s = 0.0f;
    for (int i = threadIdx.x; i < B_SZ; i += 256) s += partials[i];
    #pragma unroll
    for (int off = 32; off; off >>= 1)
        s += __shfl_xor(s, off, 64);
    __shared__ float wacc[4];
    const int wave = threadIdx.x >> 6, lane = threadIdx.x & 63;
    if (lane == 0) wacc[wave] = s;
    __syncthreads();
    if (threadIdx.x == 0) out[0] = wacc[0] + wacc[1] + wacc[2] + wacc[3];
}

extern "C" void kernel_launch(void* const* d_in, const int* in_sizes, int n_in,
                              void* d_out, int out_size, void* d_ws, size_t ws_size,
                              hipStream_t stream) {
    const float* inputs  = (const float*)d_in[0];
    const float* decoded = (const float*)d_in[1];
    const int*   labels  = (const int*)d_in[2];
    // d_in[3] is obj (==0 in setup) -> obj=False branch implemented.
    float* out      = (float*)d_out;
    float* partials = (float*)d_ws;   // B_SZ floats, fully overwritten each call

    score_kernel<<<B_SZ, 256, 0, stream>>>(inputs, decoded, labels, partials);
    reduce_kernel<<<1, 256, 0, stream>>>(partials, out);
}